// Round 1
// baseline (29.633 us; speedup 1.0000x reference)
//
#include <hip/hip_runtime.h>

// StealNMSLoss on MI355X.
//
// Mathematical simplification: the four angle masks partition [0,180) and
// angle always lies in [0,180), so sum_c mask_c == 1 per pixel. Therefore
//   loss = -sum(log_norm) / (B*4*H*W)
// and the entire Sobel/angle pipeline on true_labels cancels out.
// log_norm = log(clip(ep/resp, 1e-6, 1)), ep = exp(pred/0.1),
// resp = vertical 5-tap sum of ep (reflect padding) + 1e-6.

#define HH 1024
#define WW 1024
#define NB 8
#define RPB 32   // rows per block strip
#define TPB 256  // threads per block = columns per tile

__global__ __launch_bounds__(TPB) void nms_loss_kernel(const float* __restrict__ pred,
                                                       float* __restrict__ out) {
    const int tx = threadIdx.x;
    const int bx = blockIdx.x;         // grid = 4 col-tiles * 32 strips * 8 batches = 1024
    const int xt = bx & 3;             // column tile (1024/256)
    const int ys = (bx >> 2) & 31;     // row strip (1024/32)
    const int b  = bx >> 7;            // batch
    const int x  = xt * TPB + tx;
    const int y0 = ys * RPB;
    const float* img = pred + ((size_t)b * (HH * WW)) + x;

    // reflect-padded exp load for row y (np.pad 'reflect': -1 -> 1, H -> H-2)
    auto eload = [&](int y) {
        int r = y < 0 ? -y : y;
        if (r >= HH) r = 2 * (HH - 1) - r;
        return __expf(img[(size_t)r * WW] * 10.0f);
    };

    float e0 = eload(y0 - 2);
    float e1 = eload(y0 - 1);
    float e2 = eload(y0);
    float e3 = eload(y0 + 1);
    float acc = 0.0f;
#pragma unroll 4
    for (int i = 0; i < RPB; ++i) {
        float e4 = eload(y0 + i + 2);
        float resp = e0 + e1 + e2 + e3 + e4 + 1e-6f;
        float ratio = e2 / resp;                 // center of the 5-window
        ratio = fminf(fmaxf(ratio, 1e-6f), 1.0f);
        acc += __logf(ratio);
        e0 = e1; e1 = e2; e2 = e3; e3 = e4;
    }

    // wave-64 reduction
#pragma unroll
    for (int off = 32; off > 0; off >>= 1)
        acc += __shfl_down(acc, off, 64);

    __shared__ float wsum[TPB / 64];
    if ((tx & 63) == 0) wsum[tx >> 6] = acc;
    __syncthreads();
    if (tx == 0) {
        float s = wsum[0] + wsum[1] + wsum[2] + wsum[3];
        atomicAdd(out, s * (-1.0f / 33554432.0f));  // / (B*4*H*W), negated
    }
}

extern "C" void kernel_launch(void* const* d_in, const int* in_sizes, int n_in,
                              void* d_out, int out_size, void* d_ws, size_t ws_size,
                              hipStream_t stream) {
    const float* pred = (const float*)d_in[0];   // pred_labels [8,1,1024,1024] f32
    // d_in[1] (true_labels) is mathematically unused — masks sum to 1.
    float* out = (float*)d_out;
    hipMemsetAsync(out, 0, sizeof(float), stream);   // graph-capture-safe zero init
    nms_loss_kernel<<<NB * (HH / RPB) * (WW / TPB), TPB, 0, stream>>>(pred, out);
}

// Round 2
// 23.384 us; speedup vs baseline: 1.2672x; 1.2672x over previous
//
#include <hip/hip_runtime.h>

// StealNMSLoss on MI355X.
//
// Mathematical simplification (verified round 1, absmax 0.0): the four angle
// masks partition [0,180) and angle always lies in [0,180), so sum_c mask_c
// == 1 per pixel. Therefore
//   loss = -sum(log_norm) / (B*4*H*W)
// and the entire Sobel/angle pipeline on true_labels cancels out.
// log_norm = log(clip(ep/resp, 1e-6, 1)), ep = exp(p/0.1),
// resp = vertical 5-tap sum of ep (reflect padding) + 1e-6.
// Since ep/resp < 1 always (resp >= ep + positives), clip(·,·,1) is inert and
//   log_norm = max(10*p_center - log(resp), ln(1e-6))
// which removes the per-element divide.

#define HH 1024
#define WW 1024
#define NB 8
#define RPB 16            // rows per block strip -> 64 strips
#define TPB 256           // threads per block; each thread owns 4 columns
#define LN_EPS (-13.8155105579643f)   // ln(1e-6)

__global__ __launch_bounds__(TPB) void nms_loss_kernel(const float* __restrict__ pred,
                                                       float* __restrict__ out) {
    const int tx = threadIdx.x;
    const int bx = blockIdx.x;          // grid = 64 strips * 8 batches = 512
    const int ys = bx & 63;             // row strip
    const int b  = bx >> 6;             // batch
    const int y0 = ys * RPB;
    const float* img = pred + ((size_t)b << 20) + ((size_t)tx << 2);

    // reflect row index (np.pad 'reflect': -1 -> 1, H -> H-2)
    auto ld = [&](int y) -> float4 {
        int r = y < 0 ? -y : (y >= HH ? 2 * (HH - 1) - y : y);
        return *reinterpret_cast<const float4*>(img + ((size_t)r << 10));
    };

    // rolling 5-row window of exp(10*p), plus 2-delayed t = 10*p for center
    float4 r0 = ld(y0 - 2), r1 = ld(y0 - 1), r2 = ld(y0), r3 = ld(y0 + 1);
    float e0x = __expf(r0.x * 10.f), e0y = __expf(r0.y * 10.f), e0z = __expf(r0.z * 10.f), e0w = __expf(r0.w * 10.f);
    float e1x = __expf(r1.x * 10.f), e1y = __expf(r1.y * 10.f), e1z = __expf(r1.z * 10.f), e1w = __expf(r1.w * 10.f);
    float t2x = r2.x * 10.f, t2y = r2.y * 10.f, t2z = r2.z * 10.f, t2w = r2.w * 10.f;
    float t3x = r3.x * 10.f, t3y = r3.y * 10.f, t3z = r3.z * 10.f, t3w = r3.w * 10.f;
    float e2x = __expf(t2x), e2y = __expf(t2y), e2z = __expf(t2z), e2w = __expf(t2w);
    float e3x = __expf(t3x), e3y = __expf(t3y), e3z = __expf(t3z), e3w = __expf(t3w);

    float acc = 0.0f;
#pragma unroll
    for (int i = 0; i < RPB; ++i) {
        float4 rn = ld(y0 + i + 2);
        float tnx = rn.x * 10.f, tny = rn.y * 10.f, tnz = rn.z * 10.f, tnw = rn.w * 10.f;
        float e4x = __expf(tnx), e4y = __expf(tny), e4z = __expf(tnz), e4w = __expf(tnw);
        float rx = e0x + e1x + e2x + e3x + e4x + 1e-6f;
        float ry = e0y + e1y + e2y + e3y + e4y + 1e-6f;
        float rz = e0z + e1z + e2z + e3z + e4z + 1e-6f;
        float rw = e0w + e1w + e2w + e3w + e4w + 1e-6f;
        acc += fmaxf(t2x - __logf(rx), LN_EPS);
        acc += fmaxf(t2y - __logf(ry), LN_EPS);
        acc += fmaxf(t2z - __logf(rz), LN_EPS);
        acc += fmaxf(t2w - __logf(rw), LN_EPS);
        e0x = e1x; e0y = e1y; e0z = e1z; e0w = e1w;
        e1x = e2x; e1y = e2y; e1z = e2z; e1w = e2w;
        e2x = e3x; e2y = e3y; e2z = e3z; e2w = e3w;
        e3x = e4x; e3y = e4y; e3z = e4z; e3w = e4w;
        t2x = t3x; t2y = t3y; t2z = t3z; t2w = t3w;
        t3x = tnx; t3y = tny; t3z = tnz; t3w = tnw;
    }

    // wave-64 reduction
#pragma unroll
    for (int off = 32; off > 0; off >>= 1)
        acc += __shfl_down(acc, off, 64);

    __shared__ float wsum[TPB / 64];
    if ((tx & 63) == 0) wsum[tx >> 6] = acc;
    __syncthreads();
    if (tx == 0) {
        float s = wsum[0] + wsum[1] + wsum[2] + wsum[3];
        atomicAdd(out, s * (-1.0f / 33554432.0f));  // / (B*4*H*W), negated
    }
}

extern "C" void kernel_launch(void* const* d_in, const int* in_sizes, int n_in,
                              void* d_out, int out_size, void* d_ws, size_t ws_size,
                              hipStream_t stream) {
    const float* pred = (const float*)d_in[0];   // pred_labels [8,1,1024,1024] f32
    // d_in[1] (true_labels) is mathematically unused — masks sum to 1.
    float* out = (float*)d_out;
    hipMemsetAsync(out, 0, sizeof(float), stream);   // graph-capture-safe zero init
    nms_loss_kernel<<<NB * (HH / RPB), TPB, 0, stream>>>(pred, out);
}

// Round 4
// 14.754 us; speedup vs baseline: 2.0084x; 1.5849x over previous
//
#include <hip/hip_runtime.h>

// StealNMSLoss on MI355X.
//
// Mathematical simplification (verified rounds 1-2, absmax 0.0): the four
// angle masks partition [0,180) and angle always lies in [0,180), so
// sum_c mask_c == 1 per pixel. Therefore
//   loss = -sum(log_norm) / (B*4*H*W)
// and the Sobel/angle pipeline on true_labels cancels entirely.
// log_norm = log(clip(ep/resp, 1e-6, 1)), ep = exp(p/0.1),
// resp = vertical 5-tap sum of ep (reflect pad) + 1e-6.
// ep/resp < 1 always, so the upper clip is inert:
//   log_norm = max(10*p_c - log(resp), ln 1e-6)
// Base-2 form (v_exp_f32 / v_log_f32 are natively base-2):
//   u = p * (10*log2 e);  log_norm = ln2 * max(u_c - log2(sum 2^u + 1e-6), log2 1e-6)

// NOTE round 3: "__exp2f" is NOT a HIP device function (glibc macro collision).
// Use the amdgcn builtins, with __expf/__logf fallback (round-2 spellings compile).
#if defined(__has_builtin) && __has_builtin(__builtin_amdgcn_exp2f) && __has_builtin(__builtin_amdgcn_logf)
#define EXP2(x) __builtin_amdgcn_exp2f(x)
#define LOG2(x) __builtin_amdgcn_logf(x)
#else
#define EXP2(x) __expf((x) * 0.693147180559945f)
#define LOG2(x) (__logf(x) * 1.4426950408889634f)
#endif

#define HH 1024
#define WW 1024
#define NB 8
#define RPB 16                 // rows per strip -> 64 strips
#define TPB 256                // threads/block; each thread owns 2 columns
#define CT 2                   // column tiles (1024 / (256*2))
#define NBLK (NB * (HH / RPB) * CT)        // 1024 blocks = 4 blocks/CU
#define SC 14.4269504088896f               // 10 * log2(e)
#define L2EPS (-19.9315685693242f)         // log2(1e-6)

__global__ __launch_bounds__(TPB) void nms_main_kernel(const float* __restrict__ pred,
                                                       float* __restrict__ part) {
    const int tx = threadIdx.x;
    const int bx = blockIdx.x;          // [batch(8) | strip(64) | coltile(2)]
    const int ct = bx & 1;
    const int ys = (bx >> 1) & 63;
    const int b  = bx >> 7;
    const int y0 = ys * RPB;
    const float* img = pred + ((size_t)b << 20) + (ct * (TPB * 2)) + (tx * 2);

    // reflect row index (np.pad 'reflect': -1 -> 1, H -> H-2)
    auto ld = [&](int y) -> float2 {
        int r = y < 0 ? -y : (y >= HH ? 2 * (HH - 1) - y : y);
        return *reinterpret_cast<const float2*>(img + ((size_t)r << 10));
    };

    float2 r0 = ld(y0 - 2), r1 = ld(y0 - 1), r2 = ld(y0), r3 = ld(y0 + 1);
    float e0x = EXP2(r0.x * SC), e0y = EXP2(r0.y * SC);
    float e1x = EXP2(r1.x * SC), e1y = EXP2(r1.y * SC);
    float u2x = r2.x * SC, u2y = r2.y * SC;
    float u3x = r3.x * SC, u3y = r3.y * SC;
    float e2x = EXP2(u2x), e2y = EXP2(u2y);
    float e3x = EXP2(u3x), e3y = EXP2(u3y);

    float acc = 0.0f;
#pragma unroll
    for (int i = 0; i < RPB; ++i) {
        float2 rn = ld(y0 + i + 2);
        float unx = rn.x * SC, uny = rn.y * SC;
        float e4x = EXP2(unx), e4y = EXP2(uny);
        float rx = e0x + e1x + e2x + e3x + e4x + 1e-6f;
        float ry = e0y + e1y + e2y + e3y + e4y + 1e-6f;
        acc += fmaxf(u2x - LOG2(rx), L2EPS);
        acc += fmaxf(u2y - LOG2(ry), L2EPS);
        e0x = e1x; e0y = e1y;
        e1x = e2x; e1y = e2y;
        e2x = e3x; e2y = e3y;
        e3x = e4x; e3y = e4y;
        u2x = u3x; u2y = u3y;
        u3x = unx; u3y = uny;
    }

    // wave-64 reduction
#pragma unroll
    for (int off = 32; off > 0; off >>= 1)
        acc += __shfl_down(acc, off, 64);

    __shared__ float wsum[TPB / 64];
    if ((tx & 63) == 0) wsum[tx >> 6] = acc;
    __syncthreads();
    if (tx == 0)
        part[bx] = wsum[0] + wsum[1] + wsum[2] + wsum[3];   // plain store, no atomics
}

__global__ __launch_bounds__(TPB) void nms_reduce_kernel(const float* __restrict__ part,
                                                         float* __restrict__ out) {
    const int tx = threadIdx.x;
    float acc = 0.0f;
#pragma unroll
    for (int i = 0; i < NBLK / TPB; ++i)
        acc += part[i * TPB + tx];
#pragma unroll
    for (int off = 32; off > 0; off >>= 1)
        acc += __shfl_down(acc, off, 64);
    __shared__ float wsum[TPB / 64];
    if ((tx & 63) == 0) wsum[tx >> 6] = acc;
    __syncthreads();
    if (tx == 0) {
        float s = wsum[0] + wsum[1] + wsum[2] + wsum[3];
        // * ln2 (base-2 -> natural), / (B*4*H*W), negated
        out[0] = s * (-0.693147180559945f / 33554432.0f);
    }
}

extern "C" void kernel_launch(void* const* d_in, const int* in_sizes, int n_in,
                              void* d_out, int out_size, void* d_ws, size_t ws_size,
                              hipStream_t stream) {
    const float* pred = (const float*)d_in[0];   // pred_labels [8,1,1024,1024] f32
    // d_in[1] (true_labels) is mathematically unused — masks sum to 1.
    float* part = (float*)d_ws;                  // 1024 block partials
    float* out  = (float*)d_out;
    nms_main_kernel<<<NBLK, TPB, 0, stream>>>(pred, part);
    nms_reduce_kernel<<<1, TPB, 0, stream>>>(part, out);
}